// Round 2
// baseline (2618.140 us; speedup 1.0000x reference)
//
#include <hip/hip_runtime.h>

#define T_STEPS 10000
#define BATCH   512

__device__ __forceinline__ float fexp2(float x) {
#if __has_builtin(__builtin_amdgcn_exp2f)
  return __builtin_amdgcn_exp2f(x);
#else
  return exp2f(x);
#endif
}

__device__ __forceinline__ float frcp(float x) {
#if __has_builtin(__builtin_amdgcn_rcpf)
  return __builtin_amdgcn_rcpf(x);
#else
  return 1.0f / x;
#endif
}

// Quad-local permute: lane j of each quad receives from lane sel_j.
// CTRL = sel0 | sel1<<2 | sel2<<4 | sel3<<6 (DPP quad_perm encoding).
template <int CTRL>
__device__ __forceinline__ float qperm(float v) {
  int i = __builtin_bit_cast(int, v);
#if __has_builtin(__builtin_amdgcn_mov_dpp)
  int r = __builtin_amdgcn_mov_dpp(i, CTRL, 0xF, 0xF, true);
#else
  int r = __builtin_amdgcn_ds_swizzle(i, 0x8000 | CTRL);
#endif
  return __builtin_bit_cast(float, r);
}

// Roles within a quad (element b = tid>>2, role = tid&3):
//   role0: s0=f_W, s1=c_W     role1: s0=f_N, s1=c_N
//   role2: s0=f_R, s1=c_R     role3: s0=h,   s1=dummy(0)
// Cross-lane per stage (quad_perm, no select on the chain):
//   xA  = dpp<0x01>(s1): r0<-cN, r1<-cW, r2<-cW, r3<-cW(unused)
//   xBa = dpp<0x1E>(s1): r0<-cR, r2<-cN          (weights W2A; 0 on r1,r3)
//   xBb = dpp<0x1E>(s0): r1<-h,  r3<-fW          (weights W2B; 0 on r0,r2)
// Unified sigmoid form: r = rcp(1+exp2(W1*xA + W2A*xBa + W2B*xBb + W3*s1 + NB))
//   s0' = fma(a*P, r, f0 + a*Q)         P = pa*s0+pb, Q = qa*s0+qb   (1 fma from r)
//   carg= fma(cs*a*P, r, cs*(f0+a*Q))                                (1 fma from r)
//   s1' = fma(a*2*ia, rcp(1+exp2(carg)), c0 + a*(ia*s1+ib))          (1 fma from r2)
__global__ __launch_bounds__(64, 1)
void sleep_rk4_kernel(const float* __restrict__ noise,
                      const float* __restrict__ pgRRe,
                      const float* __restrict__ pgRWe,
                      const float* __restrict__ pgWNi,
                      const float* __restrict__ pgWRi,
                      const float* __restrict__ pgNRi,
                      const float* __restrict__ pgNWi,
                      float* __restrict__ out)
{
  const int tid  = (int)(blockIdx.x * 64u + threadIdx.x);
  const int b    = tid >> 2;
  const int role = tid & 3;

  const float g_RRe = *pgRRe, g_RWe = *pgRWe, g_WNi = *pgWNi;
  const float g_WRi = *pgWRi, g_NRi = *pgNRi, g_NWi = *pgNWi;

  const float L2E = 1.4426950408889634f;  // log2(e)

  float W1, W2A, W2B, W3, NSC, BB, qa, qb, pa, pb, cs, ia, ib;
  float s0, s1;
  int v0i, v1i;
  bool dostore1;

  if (role == 0) {              // f_W / c_W   (beta_W=-0.4, alpha_W=0.5, tau_W=1.5e6)
    const float SC = 2.0f * L2E / 0.5f;
    W1 = SC * g_NWi; W2A = SC * g_RWe; W2B = 0.0f; W3 = 0.0f; NSC = SC; BB = SC * 0.4f;
    qa = -1.0f / 1.5e6f; qb = 6.5f / 1.5e6f; pa = 0.0f; pb = -6.5f / 1.5e6f;
    cs = 2.0f * L2E / 5.0f; ia = -1.0f / 2.5e4f; ib = 1.0f / 2.5e4f;
    s0 = 6.0f; s1 = 0.9f; v0i = 0; v1i = 3; dostore1 = true;
  } else if (role == 1) {       // f_N / c_N   (kappa*h in arg, alpha_N=0.175, tau_N=6e5)
    const float SC = 2.0f * L2E / 0.175f;
    W1 = SC * g_WNi; W2A = 0.0f; W2B = SC * 1.5f; W3 = 0.0f; NSC = SC; BB = 0.0f;
    qa = -1.0f / 6.0e5f; qb = 5.0f / 6.0e5f; pa = 0.0f; pb = -5.0f / 6.0e5f;
    cs = 2.0f * L2E / 4.0f; ia = -1.0f / 1.0e4f; ib = 1.0f / 1.0e4f;
    s0 = 1.0e-3f; s1 = 1.0e-3f; v0i = 1; v1i = 4; dostore1 = true;
  } else if (role == 2) {       // f_R / c_R   (beta_R=-0.9, alpha_R=0.13, tau_R=6e4)
    const float SC = 2.0f * L2E / 0.13f;
    W1 = SC * g_WRi; W2A = SC * g_NRi; W2B = 0.0f; W3 = SC * g_RRe; NSC = SC; BB = SC * 0.9f;
    qa = -1.0f / 6.0e4f; qb = 5.0f / 6.0e4f; pa = 0.0f; pb = -5.0f / 6.0e4f;
    cs = 2.0f * L2E / 2.0f; ia = -1.0f / 1.0e4f; ib = 1.0f / 1.0e4f;
    s0 = 1.0e-3f; s1 = 1.0e-3f; v0i = 2; v1i = 5; dostore1 = true;
  } else {                      // h (sigmoid in same r-form; dummy c-chain stays 0)
    W1 = 0.0f; W2A = 0.0f; W2B = -5.0f * L2E; W3 = 0.0f; NSC = 0.0f; BB = 10.0f * L2E;
    qa = -1.0f / 3.06e7f; qb = 0.0f;
    pa = (1.0f / 3.06e7f - 1.0f / 3.483e7f);
    pb = 1.0f / 3.483e7f;
    cs = 0.0f; ia = 0.0f; ib = 0.0f;
    s0 = 0.5f; s1 = 0.0f; v0i = 6; v1i = 0; dostore1 = false;
  }
  const float m2c = 2.0f * ia;
  float f0 = s0, c0 = s1;

  const float* nptr = noise + b;
  float* p0 = out + v0i * BATCH + b;
  float* p1 = out + v1i * BATCH + b;

  // 8-deep register prefetch of per-step noise (fully unrolled -> static regs)
  float nb[8];
#pragma unroll
  for (int j = 0; j < 8; ++j) nb[j] = nptr[j * BATCH];

  const float R6 = 0.16666666666666666f;

  for (int t = 0; t < T_STEPS; t += 8) {
    // uniform (scalar) prefetch base; last block harmlessly re-reads its own rows
    const int tnext = (t + 8 <= T_STEPS - 8) ? (t + 8) : (T_STEPS - 8);
    const float* __restrict__ nxt = nptr + (size_t)tnext * BATCH;
#pragma unroll
    for (int j = 0; j < 8; ++j) {
      const float no = nb[j];
      nb[j] = nxt[(size_t)j * BATCH];

      const float NB = fmaf(NSC, no, BB);
      float acc0 = -3.0f * f0;   // reference comb: (-3v0+2v1+4v2+2v3+v4)/6
      float acc1 = -3.0f * c0;

      auto stage = [&](float a, float cf) {
        // cross-lane broadcasts of stage-start values (read before overwrite)
        const float xA  = qperm<0x01>(s1);
        const float xBa = qperm<0x1E>(s1);
        const float xBb = qperm<0x1E>(s0);
        // off-chain coefficient precomputes (stage-start values only)
        const float P  = fmaf(pa, s0, pb);
        const float Q  = fmaf(qa, s0, qb);
        const float AP = a * P;
        const float FQ = fmaf(a, Q, f0);
        const float CP = cs * AP;
        const float CF = cs * FQ;
        const float CC = fmaf(a, fmaf(ia, s1, ib), c0);
        const float A2 = a * m2c;
        // chain: dpp -> fma -> fma -> exp -> add -> rcp -> fma -> exp -> add -> rcp -> fma
        const float p3   = fmaf(W3, s1, NB);
        const float Tt   = fmaf(W2B, xBb, p3);
        const float sarg = fmaf(W1, xA, fmaf(W2A, xBa, Tt));
        const float e  = fexp2(sarg);
        const float r  = frcp(1.0f + e);
        const float s0n  = fmaf(AP, r, FQ);
        const float carg = fmaf(CP, r, CF);     // == cs*s0n up to ~1e-7 rel
        const float e2 = fexp2(carg);
        const float r2 = frcp(1.0f + e2);
        const float s1n = fmaf(A2, r2, CC);
        s0 = s0n; s1 = s1n;
        acc0 = fmaf(cf, s0n, acc0);
        acc1 = fmaf(cf, s1n, acc1);
      };
      stage(0.5f, 2.0f);
      stage(0.5f, 4.0f);
      stage(1.0f, 2.0f);
      stage(1.0f, 1.0f);

      // /6 via Newton-refined reciprocal (matches true division to ulp)
      float q0 = acc0 * R6; q0 = fmaf(fmaf(q0, -6.0f, acc0), R6, q0);
      float q1 = acc1 * R6; q1 = fmaf(fmaf(q1, -6.0f, acc1), R6, q1);
      s0 = q0; f0 = q0;
      s1 = q1; c0 = q1;

      *p0 = q0;
      if (dostore1) *p1 = q1;
      p0 += 7 * BATCH;
      p1 += 7 * BATCH;
    }
  }
}

extern "C" void kernel_launch(void* const* d_in, const int* in_sizes, int n_in,
                              void* d_out, int out_size, void* d_ws, size_t ws_size,
                              hipStream_t stream) {
  const float* noise = (const float*)d_in[0];
  const float* gRRe  = (const float*)d_in[1];
  const float* gRWe  = (const float*)d_in[2];
  const float* gWNi  = (const float*)d_in[3];
  const float* gWRi  = (const float*)d_in[4];
  const float* gNRi  = (const float*)d_in[5];
  const float* gNWi  = (const float*)d_in[6];
  float* out = (float*)d_out;

  sleep_rk4_kernel<<<dim3((BATCH * 4) / 64), dim3(64), 0, stream>>>(
      noise, gRRe, gRWe, gWNi, gWRi, gNRi, gNWi, out);
}

// Round 3
// 2057.321 us; speedup vs baseline: 1.2726x; 1.2726x over previous
//
#include <hip/hip_runtime.h>

#define T_STEPS 10000
#define BATCH   512

__device__ __forceinline__ float fexp2(float x) {
#if __has_builtin(__builtin_amdgcn_exp2f)
  return __builtin_amdgcn_exp2f(x);
#else
  return exp2f(x);
#endif
}

__device__ __forceinline__ float frcp(float x) {
#if __has_builtin(__builtin_amdgcn_rcpf)
  return __builtin_amdgcn_rcpf(x);
#else
  return 1.0f / x;
#endif
}

// Quad-local permute: lane j of each quad receives from lane sel_j.
template <int CTRL>
__device__ __forceinline__ float qperm(float v) {
  int i = __builtin_bit_cast(int, v);
#if __has_builtin(__builtin_amdgcn_mov_dpp)
  int r = __builtin_amdgcn_mov_dpp(i, CTRL, 0xF, 0xF, true);
#else
  int r = __builtin_amdgcn_ds_swizzle(i, 0x8000 | CTRL);
#endif
  return __builtin_bit_cast(float, r);
}

// Roles in a quad (b = tid>>2, role = tid&3):
//  r0: s0=f_W s1=c_W | r1: s0=f_N s1=c_N | r2: s0=f_R s1=c_R | r3: s0=h s1=0
// Main sigmoid sigma(y)=1/(1+2^y), y = W1*xA + W2A*xBa + W2B*xBb + W3*s1 + NB.
// Taylor-2 around per-step base yb (refreshed one step ahead with matched noise):
//   delta = y - yb  (computed via the same fma tree with bias NBm = NB - yb)
//   s0' = f0 + a*(qa*s0+qb) + a*P*(rb + d1*delta + d2*delta^2)
//       = fma(fma(APD2,delta,APD1), delta, fma(AQA,s0,BC))
// c-sigmoid (no noise in arg, f drifts ~1e-4/step): Taylor-1 around zb (8-step refresh):
//   s1' = fma(E1C, s0', fma(AIA,s1,CCK))
__global__ __launch_bounds__(64, 1)
void sleep_rk4_kernel(const float* __restrict__ noise,
                      const float* __restrict__ pgRRe,
                      const float* __restrict__ pgRWe,
                      const float* __restrict__ pgWNi,
                      const float* __restrict__ pgWRi,
                      const float* __restrict__ pgNRi,
                      const float* __restrict__ pgNWi,
                      float* __restrict__ out)
{
  const int tid  = (int)(blockIdx.x * 64u + threadIdx.x);
  const int b    = tid >> 2;
  const int role = tid & 3;

  const float g_RRe = *pgRRe, g_RWe = *pgRWe, g_WNi = *pgWNi;
  const float g_WRi = *pgWRi, g_NRi = *pgNRi, g_NWi = *pgNWi;

  const float L2E = 1.4426950408889634f;  // log2(e)
  const float LN2 = 0.6931471805599453f;  // ln(2)

  float W1, W2A, W2B, W3, NSC, BB, qa, qb, pa, pb, cs, ia, ib;
  float s0, s1;
  int v0i, v1i;
  bool dostore1;

  if (role == 0) {              // f_W / c_W
    const float SC = 2.0f * L2E / 0.5f;
    W1 = SC * g_NWi; W2A = SC * g_RWe; W2B = 0.0f; W3 = 0.0f; NSC = SC; BB = SC * 0.4f;
    qa = -1.0f / 1.5e6f; qb = 6.5f / 1.5e6f; pa = 0.0f; pb = -6.5f / 1.5e6f;
    cs = 2.0f * L2E / 5.0f; ia = -1.0f / 2.5e4f; ib = 1.0f / 2.5e4f;
    s0 = 6.0f; s1 = 0.9f; v0i = 0; v1i = 3; dostore1 = true;
  } else if (role == 1) {       // f_N / c_N
    const float SC = 2.0f * L2E / 0.175f;
    W1 = SC * g_WNi; W2A = 0.0f; W2B = SC * 1.5f; W3 = 0.0f; NSC = SC; BB = 0.0f;
    qa = -1.0f / 6.0e5f; qb = 5.0f / 6.0e5f; pa = 0.0f; pb = -5.0f / 6.0e5f;
    cs = 2.0f * L2E / 4.0f; ia = -1.0f / 1.0e4f; ib = 1.0f / 1.0e4f;
    s0 = 1.0e-3f; s1 = 1.0e-3f; v0i = 1; v1i = 4; dostore1 = true;
  } else if (role == 2) {       // f_R / c_R
    const float SC = 2.0f * L2E / 0.13f;
    W1 = SC * g_WRi; W2A = SC * g_NRi; W2B = 0.0f; W3 = SC * g_RRe; NSC = SC; BB = SC * 0.9f;
    qa = -1.0f / 6.0e4f; qb = 5.0f / 6.0e4f; pa = 0.0f; pb = -5.0f / 6.0e4f;
    cs = 2.0f * L2E / 2.0f; ia = -1.0f / 1.0e4f; ib = 1.0f / 1.0e4f;
    s0 = 1.0e-3f; s1 = 1.0e-3f; v0i = 2; v1i = 5; dostore1 = true;
  } else {                      // h (P uses step-start h: err ~1e-16)
    W1 = 0.0f; W2A = 0.0f; W2B = -5.0f * L2E; W3 = 0.0f; NSC = 0.0f; BB = 10.0f * L2E;
    qa = -1.0f / 3.06e7f; qb = 0.0f;
    pa = (1.0f / 3.06e7f - 1.0f / 3.483e7f);
    pb = 1.0f / 3.483e7f;
    cs = 0.0f; ia = 0.0f; ib = 0.0f;
    s0 = 0.5f; s1 = 0.0f; v0i = 6; v1i = 0; dostore1 = false;
  }

  // per-a constants (a = 0.5 for stages 0,1; a = 1.0 for stages 2,3)
  const float qbh = 0.5f * qb;
  const float AQAh = 0.5f * qa, AQA1 = qa;
  const float A2h = ia, A21 = 2.0f * ia;     // a*2*ia
  const float AIAh = 0.5f * ia, AIA1 = ia;
  const float ibh = 0.5f * ib;

  float f0 = s0, c0 = s1;

  const float* nptr = noise + b;
  float* p0 = out + v0i * BATCH + b;
  float* p1 = out + v1i * BATCH + b;

  float nb[8];
#pragma unroll
  for (int j = 0; j < 8; ++j) nb[j] = nptr[(size_t)j * BATCH];

  // ---- prologue: exact bases for step 0 ----
  float NB = fmaf(NSC, nb[0], BB);
  float yb;
  {
    const float xA = qperm<0x01>(s1);
    const float xBa = qperm<0x1E>(s1);
    const float xBb = qperm<0x1E>(s0);
    yb = fmaf(W1, xA, fmaf(W2A, xBa, fmaf(W2B, xBb, fmaf(W3, s1, NB))));
  }
  float e0 = fexp2(yb);
  float rb = frcp(1.0f + e0);
  float tb = fmaf(rb, rb, -rb);
  float d1 = LN2 * tb;
  float wb = fmaf(-2.0f, rb, 1.0f);
  float d2 = (-0.5f * LN2 * LN2) * (tb * wb);
  float NBm = NB - yb;

  float zb = cs * s0;
  float ez = fexp2(zb);
  float sbv = frcp(1.0f + ez);
  float t2 = fmaf(sbv, sbv, -sbv);
  float e1 = LN2 * t2;
  float vC = fmaf(-e1, zb, sbv);
  float E1Ch = (A2h * cs) * e1, E1C1 = (A21 * cs) * e1;

  const float R6 = 0.16666666666666666f;

  for (int t = 0; t < T_STEPS; t += 8) {
    const int tnext = (t + 8 <= T_STEPS - 8) ? (t + 8) : (T_STEPS - 8);
    const float* __restrict__ nxt = nptr + (size_t)tnext * BATCH;
#pragma unroll
    for (int j = 0; j < 8; ++j) {
      const float no_next = nb[(j + 1) & 7];   // j<7: pre-overwrite; j==7: nb[0] already = noise[t+8]
      nb[j] = nxt[(size_t)j * BATCH];

      // ---- per-step folds (off chain) ----
      const float P    = fmaf(pa, f0, pb);
      const float APh  = 0.5f * P;
      const float APD1h = APh * d1, APD11 = P * d1;
      const float APD2h = APh * d2, APD21 = P * d2;
      const float BCh = fmaf(APh, rb, f0 + qbh);
      const float BC1 = fmaf(P,   rb, f0 + qb);
      const float CCKh = fmaf(A2h, vC, c0 + ibh);
      const float CCK1 = fmaf(A21, vC, c0 + ib);
      const float NB_next = fmaf(NSC, no_next, BB);
      const float dNB = NB_next - NB;

      float acc0 = -3.0f * f0;
      float acc1 = -3.0f * c0;

      auto stage = [&](float AQA, float APD1_, float APD2_, float BC,
                       float AIA_, float CCK, float E1C_, float cf) -> float {
        const float xA  = qperm<0x01>(s1);
        const float xBa = qperm<0x1E>(s1);
        const float xBb = qperm<0x1E>(s0);
        const float B0  = fmaf(AQA, s0, BC);
        const float CCB = fmaf(AIA_, s1, CCK);
        float tt = fmaf(W3, s1, NBm);
        tt = fmaf(W2B, xBb, tt);
        tt = fmaf(W1, xA, tt);
        const float dl  = fmaf(W2A, xBa, tt);
        const float u1  = fmaf(APD2_, dl, APD1_);
        const float s0n = fmaf(u1, dl, B0);
        const float s1n = fmaf(E1C_, s0n, CCB);
        s0 = s0n; s1 = s1n;
        acc0 = fmaf(cf, s0n, acc0);
        acc1 = fmaf(cf, s1n, acc1);
        return dl;
      };

      const float d0 = stage(AQAh, APD1h, APD2h, BCh, AIAh, CCKh, E1Ch, 2.0f);

      // ---- next-step main base (off chain, hides under stages 1-3) ----
      const float ybn = (yb + d0) + dNB;
      const float en  = fexp2(ybn);
      const float rbn = frcp(1.0f + en);
      const float tbn = fmaf(rbn, rbn, -rbn);
      const float d1n = LN2 * tbn;
      const float wbn = fmaf(-2.0f, rbn, 1.0f);
      const float d2n = (-0.5f * LN2 * LN2) * (tbn * wbn);
      const float NBmn = NB_next - ybn;

      // ---- c-base refresh every 8 steps, around f[1] of this step ----
      float zbn = zb, sbn = sbv, e1n = e1;
      if (j == 0) {
        zbn = cs * s0;
        const float ezn = fexp2(zbn);
        sbn = frcp(1.0f + ezn);
        const float t2n = fmaf(sbn, sbn, -sbn);
        e1n = LN2 * t2n;
      }

      stage(AQAh, APD1h, APD2h, BCh, AIAh, CCKh, E1Ch, 4.0f);
      stage(AQA1, APD11, APD21, BC1, AIA1, CCK1, E1C1, 2.0f);
      stage(AQA1, APD11, APD21, BC1, AIA1, CCK1, E1C1, 1.0f);

      // combine: (-3v0+2v1+4v2+2v3+v4)/6, Newton-refined /6
      float q0 = acc0 * R6; q0 = fmaf(fmaf(q0, -6.0f, acc0), R6, q0);
      float q1 = acc1 * R6; q1 = fmaf(fmaf(q1, -6.0f, acc1), R6, q1);
      s0 = f0 = q0;
      s1 = c0 = q1;

      *p0 = q0;
      if (dostore1) *p1 = q1;
      p0 += 7 * BATCH;
      p1 += 7 * BATCH;

      // install next-step bases
      yb = ybn; rb = rbn; d1 = d1n; d2 = d2n; NBm = NBmn; NB = NB_next;
      if (j == 0) {
        zb = zbn; sbv = sbn; e1 = e1n;
        vC = fmaf(-e1, zb, sbv);
        E1Ch = (A2h * cs) * e1;
        E1C1 = (A21 * cs) * e1;
      }
    }
  }
}

extern "C" void kernel_launch(void* const* d_in, const int* in_sizes, int n_in,
                              void* d_out, int out_size, void* d_ws, size_t ws_size,
                              hipStream_t stream) {
  const float* noise = (const float*)d_in[0];
  const float* gRRe  = (const float*)d_in[1];
  const float* gRWe  = (const float*)d_in[2];
  const float* gWNi  = (const float*)d_in[3];
  const float* gWRi  = (const float*)d_in[4];
  const float* gNRi  = (const float*)d_in[5];
  const float* gNWi  = (const float*)d_in[6];
  float* out = (float*)d_out;

  sleep_rk4_kernel<<<dim3((BATCH * 4) / 64), dim3(64), 0, stream>>>(
      noise, gRRe, gRWe, gWNi, gWRi, gNRi, gNWi, out);
}

// Round 4
// 1296.290 us; speedup vs baseline: 2.0197x; 1.5871x over previous
//
#include <hip/hip_runtime.h>

#define T_STEPS 10000
#define BATCH   512

__device__ __forceinline__ float fexp2(float x) {
#if __has_builtin(__builtin_amdgcn_exp2f)
  return __builtin_amdgcn_exp2f(x);
#else
  return exp2f(x);
#endif
}

__device__ __forceinline__ float frcp(float x) {
#if __has_builtin(__builtin_amdgcn_rcpf)
  return __builtin_amdgcn_rcpf(x);
#else
  return 1.0f / x;
#endif
}

// Quad-local permute: lane j of each quad receives from lane sel_j.
// CTRL = sel0 | sel1<<2 | sel2<<4 | sel3<<6.
template <int CTRL>
__device__ __forceinline__ float qperm(float v) {
  int i = __builtin_bit_cast(int, v);
#if __has_builtin(__builtin_amdgcn_mov_dpp)
  int r = __builtin_amdgcn_mov_dpp(i, CTRL, 0xF, 0xF, true);
#else
  int r = __builtin_amdgcn_ds_swizzle(i, 0x8000 | CTRL);
#endif
  return __builtin_bit_cast(float, r);
}

// Roles in a quad (b = tid>>2, role = tid&3):
//  r0: s0=f_W s1=c_W | r1: s0=f_N s1=c_N | r2: s0=f_R s1=c_R | r3: s0=h s1=0
//
// Frozen-midpoint scheme: all coupling states entering the f-sigmoid are
// replaced by midpoint extrapolations m = x + 1.5*dx_prev (targets the mean
// of the RK4 stage-start samples; leading error cancels under RK weights).
// Then y is a per-step constant:
//   y = W1*dpp01(mc) + W2A*dpp1E(mc) + W2B*dpp1E(mf) + W3*mc + NB
//   sigma = rcp(1+exp2(y))  -- computed during the PREVIOUS step (off-chain)
// Per stage (exact in the damping terms):
//   s0' = fma(a*qa, s0, C_a)              C_a = f0 + a*(qb + P*sigma)
//   s1' = fma(a*ia, s1, fma(E1C_a, s0', D_a))   (c-sigmoid affine, 8-step refresh)
__global__ __launch_bounds__(64, 1)
void sleep_rk4_kernel(const float* __restrict__ noise,
                      const float* __restrict__ pgRRe,
                      const float* __restrict__ pgRWe,
                      const float* __restrict__ pgWNi,
                      const float* __restrict__ pgWRi,
                      const float* __restrict__ pgNRi,
                      const float* __restrict__ pgNWi,
                      float* __restrict__ out)
{
  const int tid  = (int)(blockIdx.x * 64u + threadIdx.x);
  const int b    = tid >> 2;
  const int role = tid & 3;

  const float g_RRe = *pgRRe, g_RWe = *pgRWe, g_WNi = *pgWNi;
  const float g_WRi = *pgWRi, g_NRi = *pgNRi, g_NWi = *pgNWi;

  const float L2E = 1.4426950408889634f;
  const float LN2 = 0.6931471805599453f;

  float W1, W2A, W2B, W3, NSC, BB, qa, qb, pa, pb, cs, ia, ib;
  float f0, c0;
  int v0i, v1i;
  bool dostore1;

  if (role == 0) {              // f_W / c_W
    const float SC = 2.0f * L2E / 0.5f;
    W1 = SC * g_NWi; W2A = SC * g_RWe; W2B = 0.0f; W3 = 0.0f; NSC = SC; BB = SC * 0.4f;
    qa = -1.0f / 1.5e6f; qb = 6.5f / 1.5e6f; pa = 0.0f; pb = -6.5f / 1.5e6f;
    cs = 2.0f * L2E / 5.0f; ia = -1.0f / 2.5e4f; ib = 1.0f / 2.5e4f;
    f0 = 6.0f; c0 = 0.9f; v0i = 0; v1i = 3; dostore1 = true;
  } else if (role == 1) {       // f_N / c_N
    const float SC = 2.0f * L2E / 0.175f;
    W1 = SC * g_WNi; W2A = 0.0f; W2B = SC * 1.5f; W3 = 0.0f; NSC = SC; BB = 0.0f;
    qa = -1.0f / 6.0e5f; qb = 5.0f / 6.0e5f; pa = 0.0f; pb = -5.0f / 6.0e5f;
    cs = 2.0f * L2E / 4.0f; ia = -1.0f / 1.0e4f; ib = 1.0f / 1.0e4f;
    f0 = 1.0e-3f; c0 = 1.0e-3f; v0i = 1; v1i = 4; dostore1 = true;
  } else if (role == 2) {       // f_R / c_R
    const float SC = 2.0f * L2E / 0.13f;
    W1 = SC * g_WRi; W2A = SC * g_NRi; W2B = 0.0f; W3 = SC * g_RRe; NSC = SC; BB = SC * 0.9f;
    qa = -1.0f / 6.0e4f; qb = 5.0f / 6.0e4f; pa = 0.0f; pb = -5.0f / 6.0e4f;
    cs = 2.0f * L2E / 2.0f; ia = -1.0f / 1.0e4f; ib = 1.0f / 1.0e4f;
    f0 = 1.0e-3f; c0 = 1.0e-3f; v0i = 2; v1i = 5; dostore1 = true;
  } else {                      // h (dummy c-chain stays 0)
    W1 = 0.0f; W2A = 0.0f; W2B = -5.0f * L2E; W3 = 0.0f; NSC = 0.0f; BB = 10.0f * L2E;
    qa = -1.0f / 3.06e7f; qb = 0.0f;
    pa = (1.0f / 3.06e7f - 1.0f / 3.483e7f);
    pb = 1.0f / 3.483e7f;
    cs = 0.0f; ia = 0.0f; ib = 0.0f;
    f0 = 0.5f; c0 = 0.0f; v0i = 6; v1i = 0; dostore1 = false;
  }

  const float AQAh = 0.5f * qa, AQA1 = qa;
  const float AIAh = 0.5f * ia, AIA1 = ia;
  const float IAC  = ia * cs;          // E1C_a = 2a*ia*e1*cs
  const float TIA  = 2.0f * ia;

  float dF = 0.0f, dC = 0.0f;

  const float* nptr = noise + b;
  float* ob = out + b;                  // uniform-advance base; per-lane fixed idx
  const int o0 = v0i * BATCH, o1 = v1i * BATCH;

  // 16-deep register noise ring (T_STEPS % 16 == 0)
  float nb[16];
#pragma unroll
  for (int j = 0; j < 16; ++j) nb[j] = nptr[(size_t)j * BATCH];

  // ---- c-sigmoid affine refresh (around current f) ----
  float E1Ch, E1C1, VDh, VD1;
  auto crefresh = [&](float fcur) {
    const float zb = cs * fcur;
    const float ez = fexp2(zb);
    const float sc = frcp(1.0f + ez);
    const float t2 = fmaf(sc, sc, -sc);
    const float e1 = LN2 * t2;                  // d(sigma_c)/dz
    const float vC = fmaf(-e1, zb, sc);         // sigma_c(z) ~ e1*z + vC
    E1C1 = (2.0f * IAC) * e1;  E1Ch = IAC * e1;
    VD1  = fmaf(TIA, vC, ib);  VDh  = 0.5f * VD1;
  };
  crefresh(f0);

  // ---- main-sigma package for a given step (uses midpoint-extrapolated coupling) ----
  // returns G = qb + P*sigma
  auto makeG = [&](float no_step, float dCl, float dFl) -> float {
    const float NBv = fmaf(NSC, no_step, BB);
    const float mc  = fmaf(1.5f, dCl, c0);
    const float mf  = fmaf(1.5f, dFl, f0);
    const float xA  = qperm<0x01>(mc);
    const float xBa = qperm<0x1E>(mc);
    const float xBb = qperm<0x1E>(mf);
    float Yc = fmaf(W3, mc, NBv);
    Yc = fmaf(W2B, xBb, Yc);
    Yc = fmaf(W2A, xBa, Yc);
    Yc = fmaf(W1, xA, Yc);
    const float sg  = fexp2(Yc);
    const float rb  = frcp(1.0f + sg);
    const float P   = fmaf(pa, f0, pb);
    return fmaf(P, rb, qb);
  };

  // prologue: package for step 0 (no history: d=0)
  float G = makeG(nb[0], 0.0f, 0.0f);
  float Ch = fmaf(0.5f, G, f0), C1 = f0 + G;
  float Dh = c0 + VDh,          D1 = c0 + VD1;

  const float R6 = 0.16666666666666666f;

  for (int t = 0; t < T_STEPS; t += 16) {
    const int tnext = (t + 16 <= T_STEPS - 16) ? (t + 16) : (T_STEPS - 16);
    const float* __restrict__ nxt = nptr + (size_t)tnext * BATCH;
#pragma unroll
    for (int j = 0; j < 16; ++j) {
      const float no_next = nb[(j + 1) & 15];   // noise of step t+j+1
      nb[j] = nxt[(size_t)j * BATCH];

      // package for step s+1 (entirely off the chain; uses step-start state)
      const float Gn = makeG(no_next, dC, dF);

      // ---- 4 RK stages of step s ----
      float s0 = f0, s1 = c0;
      float acc0 = -3.0f * f0;
      float acc1 = -3.0f * c0;

      auto stage = [&](float AQA, float CX, float DX, float E1C_, float AIA_, float cf) {
        const float s0n = fmaf(AQA, s0, CX);
        const float Tt  = fmaf(E1C_, s0n, DX);
        const float s1n = fmaf(AIA_, s1, Tt);
        s0 = s0n; s1 = s1n;
        acc0 = fmaf(cf, s0n, acc0);
        acc1 = fmaf(cf, s1n, acc1);
      };
      stage(AQAh, Ch, Dh, E1Ch, AIAh, 2.0f);
      stage(AQAh, Ch, Dh, E1Ch, AIAh, 4.0f);
      stage(AQA1, C1, D1, E1C1, AIA1, 2.0f);
      stage(AQA1, C1, D1, E1C1, AIA1, 1.0f);

      // combine (-3v0+2v1+4v2+2v3+v4)/6, Newton-refined /6
      float q0 = acc0 * R6; q0 = fmaf(fmaf(q0, -6.0f, acc0), R6, q0);
      float q1 = acc1 * R6; q1 = fmaf(fmaf(q1, -6.0f, acc1), R6, q1);

      // c-sigmoid refresh every 8 steps (uses freshest f)
      if ((j & 7) == 0) crefresh(q0);

      // boundary installs for step s+1
      dF = q0 - f0; dC = q1 - c0;
      f0 = q0; c0 = q1;
      Ch = fmaf(0.5f, Gn, q0); C1 = q0 + Gn;
      Dh = q1 + VDh;           D1 = q1 + VD1;

      // stores (uniform base in SGPR, constant per-lane offsets)
      ob[o0] = q0;
      if (dostore1) ob[o1] = q1;
      ob += 7 * BATCH;
    }
  }
}

extern "C" void kernel_launch(void* const* d_in, const int* in_sizes, int n_in,
                              void* d_out, int out_size, void* d_ws, size_t ws_size,
                              hipStream_t stream) {
  const float* noise = (const float*)d_in[0];
  const float* gRRe  = (const float*)d_in[1];
  const float* gRWe  = (const float*)d_in[2];
  const float* gWNi  = (const float*)d_in[3];
  const float* gWRi  = (const float*)d_in[4];
  const float* gNRi  = (const float*)d_in[5];
  const float* gNWi  = (const float*)d_in[6];
  float* out = (float*)d_out;

  sleep_rk4_kernel<<<dim3((BATCH * 4) / 64), dim3(64), 0, stream>>>(
      noise, gRRe, gRWe, gWNi, gWRi, gNRi, gNWi, out);
}

// Round 5
// 845.135 us; speedup vs baseline: 3.0979x; 1.5338x over previous
//
#include <hip/hip_runtime.h>

#define T_STEPS 10000
#define BATCH   512

__device__ __forceinline__ float fexp2(float x) {
#if __has_builtin(__builtin_amdgcn_exp2f)
  return __builtin_amdgcn_exp2f(x);
#else
  return exp2f(x);
#endif
}

__device__ __forceinline__ float frcp(float x) {
#if __has_builtin(__builtin_amdgcn_rcpf)
  return __builtin_amdgcn_rcpf(x);
#else
  return 1.0f / x;
#endif
}

// Quad-local permute: lane j of each quad receives from lane sel_j.
template <int CTRL>
__device__ __forceinline__ float qperm(float v) {
  int i = __builtin_bit_cast(int, v);
#if __has_builtin(__builtin_amdgcn_mov_dpp)
  int r = __builtin_amdgcn_mov_dpp(i, CTRL, 0xF, 0xF, true);
#else
  int r = __builtin_amdgcn_ds_swizzle(i, 0x8000 | CTRL);
#endif
  return __builtin_bit_cast(float, r);
}

// Roles in a quad (b = tid>>2, role = tid&3):
//  r0: s0=f_W s1=c_W | r1: s0=f_N s1=c_N | r2: s0=f_R s1=c_R | r3: s0=h s1=0
//
// R4-validated approximations kept unchanged:
//  * main sigmoid frozen per step at midpoint-extrapolated coupling
//    m = x(s) + 1.5*dx(s-1); sigma computed one step ahead (off-chain)
//  * c-sigmoid affine (slope e1, offset vC), refreshed every 8 steps
// New in R5 (pure re-association, no new approximation):
//  the 4-stage RK recursion is affine per step -> closed form
//    q0 = KF*f0 + KG*G
//    q1 = KC*c0 + e1*(LA*f0 + LB*G) + KW*VD1
//  with KF,KG,KC,LA,LB,KW extracted at init by basis-running the exact
//  stage recursion (identical arithmetic order as R4, incl Newton /6).
__global__ __launch_bounds__(64, 1)
void sleep_rk4_kernel(const float* __restrict__ noise,
                      const float* __restrict__ pgRRe,
                      const float* __restrict__ pgRWe,
                      const float* __restrict__ pgWNi,
                      const float* __restrict__ pgWRi,
                      const float* __restrict__ pgNRi,
                      const float* __restrict__ pgNWi,
                      float* __restrict__ out)
{
  const int tid  = (int)(blockIdx.x * 64u + threadIdx.x);
  const int b    = tid >> 2;
  const int role = tid & 3;

  const float g_RRe = *pgRRe, g_RWe = *pgRWe, g_WNi = *pgWNi;
  const float g_WRi = *pgWRi, g_NRi = *pgNRi, g_NWi = *pgNWi;

  const float L2E = 1.4426950408889634f;
  const float LN2 = 0.6931471805599453f;

  float W1, W2A, W2B, W3, NSC, BB, qa, qb, pa, pb, cs, ia, ib;
  float f0, c0;
  int v0i, v1i;
  bool dostore1;

  if (role == 0) {              // f_W / c_W
    const float SC = 2.0f * L2E / 0.5f;
    W1 = SC * g_NWi; W2A = SC * g_RWe; W2B = 0.0f; W3 = 0.0f; NSC = SC; BB = SC * 0.4f;
    qa = -1.0f / 1.5e6f; qb = 6.5f / 1.5e6f; pa = 0.0f; pb = -6.5f / 1.5e6f;
    cs = 2.0f * L2E / 5.0f; ia = -1.0f / 2.5e4f; ib = 1.0f / 2.5e4f;
    f0 = 6.0f; c0 = 0.9f; v0i = 0; v1i = 3; dostore1 = true;
  } else if (role == 1) {       // f_N / c_N
    const float SC = 2.0f * L2E / 0.175f;
    W1 = SC * g_WNi; W2A = 0.0f; W2B = SC * 1.5f; W3 = 0.0f; NSC = SC; BB = 0.0f;
    qa = -1.0f / 6.0e5f; qb = 5.0f / 6.0e5f; pa = 0.0f; pb = -5.0f / 6.0e5f;
    cs = 2.0f * L2E / 4.0f; ia = -1.0f / 1.0e4f; ib = 1.0f / 1.0e4f;
    f0 = 1.0e-3f; c0 = 1.0e-3f; v0i = 1; v1i = 4; dostore1 = true;
  } else if (role == 2) {       // f_R / c_R
    const float SC = 2.0f * L2E / 0.13f;
    W1 = SC * g_WRi; W2A = SC * g_NRi; W2B = 0.0f; W3 = SC * g_RRe; NSC = SC; BB = SC * 0.9f;
    qa = -1.0f / 6.0e4f; qb = 5.0f / 6.0e4f; pa = 0.0f; pb = -5.0f / 6.0e4f;
    cs = 2.0f * L2E / 2.0f; ia = -1.0f / 1.0e4f; ib = 1.0f / 1.0e4f;
    f0 = 1.0e-3f; c0 = 1.0e-3f; v0i = 2; v1i = 5; dostore1 = true;
  } else {                      // h
    W1 = 0.0f; W2A = 0.0f; W2B = -5.0f * L2E; W3 = 0.0f; NSC = 0.0f; BB = 10.0f * L2E;
    qa = -1.0f / 3.06e7f; qb = 0.0f;
    pa = (1.0f / 3.06e7f - 1.0f / 3.483e7f);
    pb = 1.0f / 3.483e7f;
    cs = 0.0f; ia = 0.0f; ib = 0.0f;
    f0 = 0.5f; c0 = 0.0f; v0i = 6; v1i = 0; dostore1 = false;
  }

  const float AQAh = 0.5f * qa, AQA1 = qa;
  const float AIAh = 0.5f * ia, AIA1 = ia;
  const float IAC  = ia * cs;
  const float TIA  = 2.0f * ia;
  const float R6   = 0.16666666666666666f;

  // ---- init: extract closed-form step coefficients via basis runs ----
  float vF[4], vG[4];
  auto frun = [&](float f0b, float Gb, float* v) -> float {
    const float Chb = fmaf(0.5f, Gb, f0b), C1b = f0b + Gb;
    float s0 = f0b, acc = -3.0f * f0b;
    s0 = fmaf(AQAh, s0, Chb); v[0] = s0; acc = fmaf(2.0f, s0, acc);
    s0 = fmaf(AQAh, s0, Chb); v[1] = s0; acc = fmaf(4.0f, s0, acc);
    s0 = fmaf(AQA1, s0, C1b); v[2] = s0; acc = fmaf(2.0f, s0, acc);
    s0 = fmaf(AQA1, s0, C1b); v[3] = s0; acc = fmaf(1.0f, s0, acc);
    float q = acc * R6; q = fmaf(fmaf(q, -6.0f, acc), R6, q); return q;
  };
  const float KF = frun(1.0f, 0.0f, vF);
  const float KG = frun(0.0f, 1.0f, vG);

  auto crun = [&](const float* v, float c0b, float e1u, float vd1) -> float {
    const float E1h = IAC * e1u, E11 = 2.0f * IAC * e1u;
    const float Dh = c0b + 0.5f * vd1, D1 = c0b + vd1;
    float s1 = c0b, acc = -3.0f * c0b;
    s1 = fmaf(AIAh, s1, fmaf(E1h, v[0], Dh)); acc = fmaf(2.0f, s1, acc);
    s1 = fmaf(AIAh, s1, fmaf(E1h, v[1], Dh)); acc = fmaf(4.0f, s1, acc);
    s1 = fmaf(AIA1, s1, fmaf(E11, v[2], D1)); acc = fmaf(2.0f, s1, acc);
    s1 = fmaf(AIA1, s1, fmaf(E11, v[3], D1)); acc = fmaf(1.0f, s1, acc);
    float q = acc * R6; q = fmaf(fmaf(q, -6.0f, acc), R6, q); return q;
  };
  float z4[4] = {0.0f, 0.0f, 0.0f, 0.0f};
  const float KC  = crun(z4, 1.0f, 0.0f, 0.0f);
  const float LAf = crun(vF, 0.0f, 1.0f, 0.0f);   // e1-slope coeff on f0
  const float LBf = crun(vG, 0.0f, 1.0f, 0.0f);   // e1-slope coeff on G
  const float KW  = crun(z4, 0.0f, 0.0f, 1.0f);   // coeff on VD1

  // ---- c-sigmoid refresh: folds e1, VD1 into per-step constants ----
  float LAe, LBe, VDK;
  auto crefresh = [&](float fcur) {
    const float zb = cs * fcur;
    const float ez = fexp2(zb);
    const float sc_ = frcp(1.0f + ez);
    const float t2 = fmaf(sc_, sc_, -sc_);
    const float e1 = LN2 * t2;
    const float vC = fmaf(-e1, zb, sc_);
    const float VD1 = fmaf(TIA, vC, ib);
    LAe = LAf * e1; LBe = LBf * e1; VDK = KW * VD1;
  };
  crefresh(f0);

  // ---- per-step sigma package: G = qb + P*sigma(y(m)) ----
  auto makeG = [&](float no_step, float dCl, float dFl) -> float {
    const float NBv = fmaf(NSC, no_step, BB);
    const float mc  = fmaf(1.5f, dCl, c0);
    const float mf  = fmaf(1.5f, dFl, f0);
    const float xA  = qperm<0x01>(mc);
    const float xBa = qperm<0x1E>(mc);
    const float xBb = qperm<0x1E>(mf);
    float Yc = fmaf(W1, xA, NBv);
    Yc = fmaf(W2A, xBa, Yc);
    Yc = fmaf(W3, mc, Yc);
    Yc = fmaf(W2B, xBb, Yc);
    const float sg = fexp2(Yc);
    const float rb = frcp(1.0f + sg);
    const float P  = fmaf(pa, f0, pb);
    return fmaf(P, rb, qb);
  };

  float dF = 0.0f, dC = 0.0f;

  const float* nptr = noise + b;
  float* ob = out + b;
  const int o0 = v0i * BATCH, o1 = v1i * BATCH;

  float nb[16];
#pragma unroll
  for (int j = 0; j < 16; ++j) nb[j] = nptr[(size_t)j * BATCH];

  float Gc = makeG(nb[0], 0.0f, 0.0f);   // G for step 0

  for (int t = 0; t < T_STEPS; t += 16) {
    const int tnext = (t + 16 <= T_STEPS - 16) ? (t + 16) : (T_STEPS - 16);
    const float* __restrict__ nxt = nptr + (size_t)tnext * BATCH;
#pragma unroll
    for (int j = 0; j < 16; ++j) {
      const float no_next = nb[(j + 1) & 15];
      nb[j] = nxt[(size_t)j * BATCH];

      // c-sigmoid refresh every 8 steps (uses step-start f: off-chain)
      if ((j & 7) == 0) crefresh(f0);

      // sigma package for step s+1 (off-chain; ~2 iterations of slack)
      const float Gn = makeG(no_next, dC, dF);

      // closed-form RK4 step s
      const float q0 = fmaf(KF, f0, KG * Gc);
      const float q1 = fmaf(KC, c0, fmaf(LAe, f0, fmaf(LBe, Gc, VDK)));

      dF = q0 - f0; dC = q1 - c0;
      f0 = q0; c0 = q1; Gc = Gn;

      ob[o0] = q0;
      if (dostore1) ob[o1] = q1;
      ob += 7 * BATCH;
    }
  }
}

extern "C" void kernel_launch(void* const* d_in, const int* in_sizes, int n_in,
                              void* d_out, int out_size, void* d_ws, size_t ws_size,
                              hipStream_t stream) {
  const float* noise = (const float*)d_in[0];
  const float* gRRe  = (const float*)d_in[1];
  const float* gRWe  = (const float*)d_in[2];
  const float* gWNi  = (const float*)d_in[3];
  const float* gWRi  = (const float*)d_in[4];
  const float* gNRi  = (const float*)d_in[5];
  const float* gNWi  = (const float*)d_in[6];
  float* out = (float*)d_out;

  sleep_rk4_kernel<<<dim3((BATCH * 4) / 64), dim3(64), 0, stream>>>(
      noise, gRRe, gRWe, gWNi, gWRi, gNRi, gNWi, out);
}

// Round 6
// 835.812 us; speedup vs baseline: 3.1325x; 1.0112x over previous
//
#include <hip/hip_runtime.h>

#define T_STEPS 10000
#define BATCH   512

__device__ __forceinline__ float fexp2(float x) {
#if __has_builtin(__builtin_amdgcn_exp2f)
  return __builtin_amdgcn_exp2f(x);
#else
  return exp2f(x);
#endif
}

__device__ __forceinline__ float frcp(float x) {
#if __has_builtin(__builtin_amdgcn_rcpf)
  return __builtin_amdgcn_rcpf(x);
#else
  return 1.0f / x;
#endif
}

// Quad-local permute: lane j of each quad receives from lane sel_j.
template <int CTRL>
__device__ __forceinline__ float qperm(float v) {
  int i = __builtin_bit_cast(int, v);
#if __has_builtin(__builtin_amdgcn_mov_dpp)
  int r = __builtin_amdgcn_mov_dpp(i, CTRL, 0xF, 0xF, true);
#else
  int r = __builtin_amdgcn_ds_swizzle(i, 0x8000 | CTRL);
#endif
  return __builtin_bit_cast(float, r);
}

// Roles in a quad (b = tid>>2, role = tid&3):
//  r0: s0=f_W s1=c_W | r1: s0=f_N s1=c_N | r2: s0=f_R s1=c_R | r3: s0=h s1=0
//
// Scheme (validated R4/R5, absmax == exact kernel's 0.0039):
//  * main sigmoid frozen per step at midpoint-extrapolated coupling;
//    R6: computed TWO steps ahead: m = x(s) + 2.5*dx(s-1)  (exp/rcp get
//    2 iterations of slack -> off the loop-carried chain entirely)
//  * c-sigmoid affine (slope e1), refreshed every 8 steps; R6: compute at
//    j%8==0, install at j%8==2 (off-chain)
//  * RK4 step in closed affine form:
//      q0 = KF*f0 + KG*G
//      q1 = KC*c0 + e1*(LA*f0 + LB*G) + KW*VD1
//    coefficients extracted at init by basis-running the exact recursion.
__global__ __launch_bounds__(64, 1)
void sleep_rk4_kernel(const float* __restrict__ noise,
                      const float* __restrict__ pgRRe,
                      const float* __restrict__ pgRWe,
                      const float* __restrict__ pgWNi,
                      const float* __restrict__ pgWRi,
                      const float* __restrict__ pgNRi,
                      const float* __restrict__ pgNWi,
                      float* __restrict__ out)
{
  const int tid  = (int)(blockIdx.x * 64u + threadIdx.x);
  const int b    = tid >> 2;
  const int role = tid & 3;

  const float g_RRe = *pgRRe, g_RWe = *pgRWe, g_WNi = *pgWNi;
  const float g_WRi = *pgWRi, g_NRi = *pgNRi, g_NWi = *pgNWi;

  const float L2E = 1.4426950408889634f;
  const float LN2 = 0.6931471805599453f;

  float W1, W2A, W2B, W3, NSC, BB, qa, qb, pa, pb, cs, ia, ib;
  float f0, c0;
  int v0i, v1i;
  bool dostore1;

  if (role == 0) {              // f_W / c_W
    const float SC = 2.0f * L2E / 0.5f;
    W1 = SC * g_NWi; W2A = SC * g_RWe; W2B = 0.0f; W3 = 0.0f; NSC = SC; BB = SC * 0.4f;
    qa = -1.0f / 1.5e6f; qb = 6.5f / 1.5e6f; pa = 0.0f; pb = -6.5f / 1.5e6f;
    cs = 2.0f * L2E / 5.0f; ia = -1.0f / 2.5e4f; ib = 1.0f / 2.5e4f;
    f0 = 6.0f; c0 = 0.9f; v0i = 0; v1i = 3; dostore1 = true;
  } else if (role == 1) {       // f_N / c_N
    const float SC = 2.0f * L2E / 0.175f;
    W1 = SC * g_WNi; W2A = 0.0f; W2B = SC * 1.5f; W3 = 0.0f; NSC = SC; BB = 0.0f;
    qa = -1.0f / 6.0e5f; qb = 5.0f / 6.0e5f; pa = 0.0f; pb = -5.0f / 6.0e5f;
    cs = 2.0f * L2E / 4.0f; ia = -1.0f / 1.0e4f; ib = 1.0f / 1.0e4f;
    f0 = 1.0e-3f; c0 = 1.0e-3f; v0i = 1; v1i = 4; dostore1 = true;
  } else if (role == 2) {       // f_R / c_R
    const float SC = 2.0f * L2E / 0.13f;
    W1 = SC * g_WRi; W2A = SC * g_NRi; W2B = 0.0f; W3 = SC * g_RRe; NSC = SC; BB = SC * 0.9f;
    qa = -1.0f / 6.0e4f; qb = 5.0f / 6.0e4f; pa = 0.0f; pb = -5.0f / 6.0e4f;
    cs = 2.0f * L2E / 2.0f; ia = -1.0f / 1.0e4f; ib = 1.0f / 1.0e4f;
    f0 = 1.0e-3f; c0 = 1.0e-3f; v0i = 2; v1i = 5; dostore1 = true;
  } else {                      // h
    W1 = 0.0f; W2A = 0.0f; W2B = -5.0f * L2E; W3 = 0.0f; NSC = 0.0f; BB = 10.0f * L2E;
    qa = -1.0f / 3.06e7f; qb = 0.0f;
    pa = (1.0f / 3.06e7f - 1.0f / 3.483e7f);
    pb = 1.0f / 3.483e7f;
    cs = 0.0f; ia = 0.0f; ib = 0.0f;
    f0 = 0.5f; c0 = 0.0f; v0i = 6; v1i = 0; dostore1 = false;
  }

  const float AQAh = 0.5f * qa, AQA1 = qa;
  const float AIAh = 0.5f * ia, AIA1 = ia;
  const float IAC  = ia * cs;
  const float TIA  = 2.0f * ia;
  const float R6   = 0.16666666666666666f;

  // ---- init: closed-form step coefficients via basis runs ----
  float vF[4], vG[4];
  auto frun = [&](float f0b, float Gb, float* v) -> float {
    const float Chb = fmaf(0.5f, Gb, f0b), C1b = f0b + Gb;
    float s0 = f0b, acc = -3.0f * f0b;
    s0 = fmaf(AQAh, s0, Chb); v[0] = s0; acc = fmaf(2.0f, s0, acc);
    s0 = fmaf(AQAh, s0, Chb); v[1] = s0; acc = fmaf(4.0f, s0, acc);
    s0 = fmaf(AQA1, s0, C1b); v[2] = s0; acc = fmaf(2.0f, s0, acc);
    s0 = fmaf(AQA1, s0, C1b); v[3] = s0; acc = fmaf(1.0f, s0, acc);
    float q = acc * R6; q = fmaf(fmaf(q, -6.0f, acc), R6, q); return q;
  };
  const float KF = frun(1.0f, 0.0f, vF);
  const float KG = frun(0.0f, 1.0f, vG);

  auto crun = [&](const float* v, float c0b, float e1u, float vd1) -> float {
    const float E1h = IAC * e1u, E11 = 2.0f * IAC * e1u;
    const float Dh = c0b + 0.5f * vd1, D1 = c0b + vd1;
    float s1 = c0b, acc = -3.0f * c0b;
    s1 = fmaf(AIAh, s1, fmaf(E1h, v[0], Dh)); acc = fmaf(2.0f, s1, acc);
    s1 = fmaf(AIAh, s1, fmaf(E1h, v[1], Dh)); acc = fmaf(4.0f, s1, acc);
    s1 = fmaf(AIA1, s1, fmaf(E11, v[2], D1)); acc = fmaf(2.0f, s1, acc);
    s1 = fmaf(AIA1, s1, fmaf(E11, v[3], D1)); acc = fmaf(1.0f, s1, acc);
    float q = acc * R6; q = fmaf(fmaf(q, -6.0f, acc), R6, q); return q;
  };
  float z4[4] = {0.0f, 0.0f, 0.0f, 0.0f};
  const float KC  = crun(z4, 1.0f, 0.0f, 0.0f);
  const float LAf = crun(vF, 0.0f, 1.0f, 0.0f);
  const float LBf = crun(vG, 0.0f, 1.0f, 0.0f);
  const float KW  = crun(z4, 0.0f, 0.0f, 1.0f);

  // ---- c-sigmoid refresh (compute & install split for pipelining) ----
  float LAe, LBe, VDK;         // live constants
  float tLAe, tLBe, tVDK;      // staged
  auto crefresh_compute = [&](float fcur) {
    const float zb = cs * fcur;
    const float ez = fexp2(zb);
    const float sc_ = frcp(1.0f + ez);
    const float t2 = fmaf(sc_, sc_, -sc_);
    const float e1 = LN2 * t2;
    const float vC = fmaf(-e1, zb, sc_);
    const float VD1 = fmaf(TIA, vC, ib);
    tLAe = LAf * e1; tLBe = LBf * e1; tVDK = KW * VD1;
  };
  crefresh_compute(f0);
  LAe = tLAe; LBe = tLBe; VDK = tVDK;

  // ---- sigma package: G = qb + P*sigma(y(m)), m extrapolated EXT steps ----
  auto makeG = [&](float no_step, float dCl, float dFl, float EXT) -> float {
    const float NBv = fmaf(NSC, no_step, BB);
    const float mc  = fmaf(EXT, dCl, c0);
    const float mf  = fmaf(EXT, dFl, f0);
    const float xA  = qperm<0x01>(mc);
    const float xBa = qperm<0x1E>(mc);
    const float xBb = qperm<0x1E>(mf);
    float Yc = fmaf(W1, xA, NBv);
    Yc = fmaf(W2A, xBa, Yc);
    Yc = fmaf(W3, mc, Yc);
    Yc = fmaf(W2B, xBb, Yc);
    const float sg = fexp2(Yc);
    const float rb = frcp(1.0f + sg);
    const float P  = fmaf(pa, f0, pb);
    return fmaf(P, rb, qb);
  };

  float dF = 0.0f, dC = 0.0f;

  const float* nptr = noise + b;
  float* ob = out + b;
  const int o0 = v0i * BATCH, o1 = v1i * BATCH;

  float nb[16];
#pragma unroll
  for (int j = 0; j < 16; ++j) nb[j] = nptr[(size_t)j * BATCH];

  // warmup: G for steps 0 and 1 (no history -> d=0)
  float G0 = makeG(nb[0], 0.0f, 0.0f, 0.0f);
  float G1 = makeG(nb[1], 0.0f, 0.0f, 0.0f);

  for (int t = 0; t < T_STEPS; t += 16) {
    const int tnext = (t + 16 <= T_STEPS - 16) ? (t + 16) : (T_STEPS - 16);
    const float* __restrict__ nxt = nptr + (size_t)tnext * BATCH;
#pragma unroll
    for (int j = 0; j < 16; ++j) {
      // staged c-sigmoid refresh: compute at j%8==0, install at j%8==2
      if ((j & 7) == 0) crefresh_compute(f0);
      if ((j & 7) == 2) { LAe = tLAe; LBe = tLBe; VDK = tVDK; }

      // G for step s+2 (2 iterations of slack; exp/rcp off-chain)
      const float no2 = nb[(j + 2) & 15];
      const float G2 = makeG(no2, dC, dF, 2.5f);

      nb[j] = nxt[(size_t)j * BATCH];

      // closed-form RK4 step s (loop-carried chain: 1-3 fma)
      const float q0 = fmaf(KF, f0, KG * G0);
      const float q1 = fmaf(KC, c0, fmaf(LAe, f0, fmaf(LBe, G0, VDK)));

      dF = q0 - f0; dC = q1 - c0;
      f0 = q0; c0 = q1;
      G0 = G1; G1 = G2;

      ob[o0] = q0;
      if (dostore1) ob[o1] = q1;
      ob += 7 * BATCH;
    }
  }
}

extern "C" void kernel_launch(void* const* d_in, const int* in_sizes, int n_in,
                              void* d_out, int out_size, void* d_ws, size_t ws_size,
                              hipStream_t stream) {
  const float* noise = (const float*)d_in[0];
  const float* gRRe  = (const float*)d_in[1];
  const float* gRWe  = (const float*)d_in[2];
  const float* gWNi  = (const float*)d_in[3];
  const float* gWRi  = (const float*)d_in[4];
  const float* gNRi  = (const float*)d_in[5];
  const float* gNWi  = (const float*)d_in[6];
  float* out = (float*)d_out;

  sleep_rk4_kernel<<<dim3((BATCH * 4) / 64), dim3(64), 0, stream>>>(
      noise, gRRe, gRWe, gWNi, gWRi, gNRi, gNWi, out);
}